// Round 8
// baseline (1055.441 us; speedup 1.0000x reference)
//
#include <hip/hip_runtime.h>
#include <math.h>

// EM routing, fully fused: one block per (b, l) output position, 256 threads.
// A=32, B=32, PSIZE=16 (4x4), K=3, STRIDE=2, PAD=1, ITERS=3.
// Input 14x14 -> output 7x7 (l = 49). kkA = 9*32 = 288.
//
// Mapping: c = tid&31 (capsule = lane bits 0-4), g = (tid>>5)&7 (k-group,
// thread owns k = 8j+g, j=0..35). r~ = r*au lives ENTIRELY in registers
// (r_reg[36], loops fully unrolled -> static indices). Softmax over c is
// intra-wave shfl butterflies. Moments: shfl_xor(32) combines the g-pair in
// each wave, then 4-wave LDS partials (s12).
//
// NOTE __launch_bounds__ 2nd arg acts as blocks/CU on this toolchain
// (R2: (512,4)->VGPR64; R7: (512,2)->VGPR128 => spill catastrophe).
// (256,2) -> 8 waves/CU -> VGPR cap 256: register structure fits, no spill.
//
// LDS 45568 B -> 2 blocks/CU co-resident (392 blocks in 512 slots, no tail).
// Barriers: 3/iter. WAR audit: red_a W(<B1)/R(B1..B2), next W after B2,B3.
// s12 W(B1..B2)/R(B2..B3), next W after B3,B1'. red_b W(B2..B3)/R(>B3),
// next W after B1',B2'. mu_t/is2_t W(B2..B3)/R(>B3 in P4), next W B2'..B3'.

#define KKA_    288
#define L_      49
#define OH_     7
#define EPSF    1e-12f
#define PUST    20              // pu row stride (80 B, 16B-aligned for b128)
#define S12ST   34              // s12 row stride (2-way bank alias = free)
#define LOG_LN2PI 0.60861006f   // log(log(2*pi))

__global__ __launch_bounds__(256, 2) void em_routing_kernel(
    const float* __restrict__ a_in,   // (8, 32, 14, 14)
    const float* __restrict__ pose,   // (8, 512, 14, 14)
    const float* __restrict__ W,      // (288, 32, 4, 4)
    const float* __restrict__ beta_u, // (32)
    const float* __restrict__ beta_a, // (32)
    float* __restrict__ out)          // a_o (8,32,7,7) then pose_out (8,512,7,7)
{
    __shared__ float pu_lds[KKA_ * PUST];    // 23040 B, au[k] at pad slot 16
    __shared__ float s12[4 * 32 * S12ST];    // 17408 B per-wave S1/S2 partials
    __shared__ float red_a[4 * 32];          //   512 B rsum partials
    __shared__ float red_b[4 * 32];          //   512 B Ls partials
    __shared__ float mu_t[16 * 32];          //  2048 B mu[p][c]
    __shared__ float is2_t[16 * 32];         //  2048 B 0.5/sigma^2 [p][c]

    const int tid = threadIdx.x;
    const int bl = blockIdx.x;
    const int b  = bl / L_;
    const int l  = bl % L_;
    const int oy = l / OH_, ox = l % OH_;

    // ---- stage pu (pose unfold patch), stride-20 rows ----
    for (int q = tid; q < KKA_ * 16; q += 256) {
        const int k = q >> 4, p = q & 15;
        const int a = k & 31, kki = k >> 5;
        const int ki = kki / 3, kj = kki % 3;
        const int iy = oy * 2 + ki - 1, ix = ox * 2 + kj - 1;
        float v = 0.f;
        if ((unsigned)iy < 14u && (unsigned)ix < 14u)
            v = pose[(b * 512 + a * 16 + p) * 196 + iy * 14 + ix];
        pu_lds[k * PUST + p] = v;
    }
    // ---- stage au into pu pad slot 16 (STRIDED: 288 > 256 threads) ----
    for (int k = tid; k < KKA_; k += 256) {
        const int a = k & 31, kki = k >> 5;
        const int ki = kki / 3, kj = kki % 3;
        const int iy = oy * 2 + ki - 1, ix = ox * 2 + kj - 1;
        float v = 0.f;
        if ((unsigned)iy < 14u && (unsigned)ix < 14u)
            v = a_in[(b * 32 + a) * 196 + iy * 14 + ix];
        pu_lds[k * PUST + 16] = v;
    }
    __syncthreads();

    const int c    = tid & 31;       // capsule (lane bits 0-4)
    const int g    = (tid >> 5) & 7; // k-group 0..7 (bit0 = lane bit 5)
    const int lane = tid & 63;
    const int w    = tid >> 6;       // wave 0..3; wave w holds g in {2w,2w+1}

    const float bu_c = beta_u[c];
    const float ba_c = beta_a[c];

    // ---- r~ = r*au in registers; init r=1 -> r~ = au ----
    float r_reg[36];
    #pragma unroll
    for (int j = 0; j < 36; ++j)
        r_reg[j] = pu_lds[((j << 3) + g) * PUST + 16];

    for (int it = 0; it < 3; ++it) {
        const float lam = (it == 0) ? 0.0005f : ((it == 1) ? 0.000975f : 0.00142625f);

        // ---- step 1: rsum[c] = sum_k r~ ----
        float pa = 0.f, pb = 0.f;
        #pragma unroll
        for (int j = 0; j < 36; j += 2) { pa += r_reg[j]; pb += r_reg[j + 1]; }
        float part = pa + pb;
        part += __shfl_xor(part, 32);           // combine g-pair within wave
        if (lane < 32) red_a[w * 32 + c] = part;
        __syncthreads();                        // B1
        float rsum = 0.f;
        #pragma unroll
        for (int ww = 0; ww < 4; ++ww) rsum += red_a[ww * 32 + c];
        const float invr = 1.0f / (rsum + EPSF);

        // ---- P23: moments over this thread's 36 k's, all 16 p's ----
        float S1[16], S2[16];
        #pragma unroll
        for (int t = 0; t < 16; ++t) { S1[t] = 0.f; S2[t] = 0.f; }
        const float* pW = W + g * 512 + c * 16;
        #pragma unroll
        for (int j = 0; j < 36; ++j) {
            const int k = (j << 3) + g;
            const float cf = r_reg[j] * invr;
            const float4 w0 = *(const float4*)(pW);
            const float4 w1 = *(const float4*)(pW + 4);
            const float4 w2 = *(const float4*)(pW + 8);
            const float4 w3 = *(const float4*)(pW + 12);
            pW += 4096;
            const float* pk = &pu_lds[k * PUST];
            #pragma unroll
            for (int i = 0; i < 4; ++i) {
                const float4 pu4 = *(const float4*)(pk + (i << 2));
                float v, cv;
                v = pu4.x * w0.x + pu4.y * w1.x + pu4.z * w2.x + pu4.w * w3.x;
                cv = cf * v; S1[i * 4 + 0] += cv; S2[i * 4 + 0] += cv * v;
                v = pu4.x * w0.y + pu4.y * w1.y + pu4.z * w2.y + pu4.w * w3.y;
                cv = cf * v; S1[i * 4 + 1] += cv; S2[i * 4 + 1] += cv * v;
                v = pu4.x * w0.z + pu4.y * w1.z + pu4.z * w2.z + pu4.w * w3.z;
                cv = cf * v; S1[i * 4 + 2] += cv; S2[i * 4 + 2] += cv * v;
                v = pu4.x * w0.w + pu4.y * w1.w + pu4.z * w2.w + pu4.w * w3.w;
                cv = cf * v; S1[i * 4 + 3] += cv; S2[i * 4 + 3] += cv * v;
            }
        }
        // combine g-pair within wave, publish per-wave partials
        #pragma unroll
        for (int t = 0; t < 16; ++t) {
            S1[t] += __shfl_xor(S1[t], 32);
            S2[t] += __shfl_xor(S2[t], 32);
        }
        if (lane < 32) {
            float* dst = &s12[(w * 32 + c) * S12ST];
            #pragma unroll
            for (int t = 0; t < 16; t += 2) {
                *(float2*)(dst + t)      = make_float2(S1[t], S1[t + 1]);
                *(float2*)(dst + 16 + t) = make_float2(S2[t], S2[t + 1]);
            }
        }
        __syncthreads();                        // B2

        // ---- stats: thread (c,g) handles p = g and p = g+8 ----
        const int pA = g, pB = g + 8;
        float mA = 0.f, eA = 0.f, mB = 0.f, eB = 0.f;
        #pragma unroll
        for (int ww = 0; ww < 4; ++ww) {
            const float* src = &s12[(ww * 32 + c) * S12ST];
            mA += src[pA];      eA += src[16 + pA];
            mB += src[pB];      eB += src[16 + pB];
        }
        const float ssA = fmaxf(eA - mA * mA, 0.f) + EPSF;
        const float ssB = fmaxf(eB - mB * mB, 0.f) + EPSF;
        float lps = __logf(ssA) + __logf(ssB);
        lps += __shfl_xor(lps, 32);             // wave w: p in {2w,2w+1,2w+8,2w+9}
        if (lane < 32) red_b[w * 32 + c] = lps;
        if (it == 2) {
            out[12544 + (b * 512 + (c << 4) + pA) * 49 + l] = mA;
            out[12544 + (b * 512 + (c << 4) + pB) * 49 + l] = mB;
        } else {
            mu_t[pA * 32 + c]  = mA;  is2_t[pA * 32 + c] = 0.5f / ssA;
            mu_t[pB * 32 + c]  = mB;  is2_t[pB * 32 + c] = 0.5f / ssB;
        }
        __syncthreads();                        // B3
        float Ls = 0.f;
        #pragma unroll
        for (int ww = 0; ww < 4; ++ww) Ls += red_b[ww * 32 + c];
        const float cost = rsum * (16.f * bu_c + 0.5f * Ls);
        const float aout = 1.f / (1.f + __expf(-(lam * (ba_c - cost))));

        if (it == 2) {
            if (g == 0) out[(b * 32 + c) * 49 + l] = aout;
        } else {
            const float m1c = -0.5f * (Ls + 16.f * LOG_LN2PI) + __logf(aout);
            // ---- P4 + in-register softmax over c (intra-wave) ----
            float mu_r[16], is2_r[16];
            #pragma unroll
            for (int pp = 0; pp < 16; ++pp) {
                mu_r[pp]  = mu_t[pp * 32 + c];
                is2_r[pp] = is2_t[pp * 32 + c];
            }
            const float* pW4 = W + g * 512 + c * 16;
            #pragma unroll
            for (int j = 0; j < 36; ++j) {
                const int k = (j << 3) + g;
                const float4 wr0 = *(const float4*)(pW4);
                const float4 wr1 = *(const float4*)(pW4 + 4);
                const float4 wr2 = *(const float4*)(pW4 + 8);
                const float4 wr3 = *(const float4*)(pW4 + 12);
                pW4 += 4096;
                float q = 0.f;
                #pragma unroll
                for (int i = 0; i < 4; ++i) {
                    const float4 pui = *(const float4*)&pu_lds[k * PUST + (i << 2)];
                    float vv, d;
                    vv = pui.x * wr0.x + pui.y * wr1.x + pui.z * wr2.x + pui.w * wr3.x;
                    d = vv - mu_r[i * 4 + 0]; q += d * d * is2_r[i * 4 + 0];
                    vv = pui.x * wr0.y + pui.y * wr1.y + pui.z * wr2.y + pui.w * wr3.y;
                    d = vv - mu_r[i * 4 + 1]; q += d * d * is2_r[i * 4 + 1];
                    vv = pui.x * wr0.z + pui.y * wr1.z + pui.z * wr2.z + pui.w * wr3.z;
                    d = vv - mu_r[i * 4 + 2]; q += d * d * is2_r[i * 4 + 2];
                    vv = pui.x * wr0.w + pui.y * wr1.w + pui.z * wr2.w + pui.w * wr3.w;
                    d = vv - mu_r[i * 4 + 3]; q += d * d * is2_r[i * 4 + 3];
                }
                const float la = m1c - q;
                // softmax over the 32 c-lanes (each 32-lane half holds all c)
                float mx = la;
                mx = fmaxf(mx, __shfl_xor(mx, 1));
                mx = fmaxf(mx, __shfl_xor(mx, 2));
                mx = fmaxf(mx, __shfl_xor(mx, 4));
                mx = fmaxf(mx, __shfl_xor(mx, 8));
                mx = fmaxf(mx, __shfl_xor(mx, 16));
                const float e = __expf(la - mx);
                float se = e;
                se += __shfl_xor(se, 1);
                se += __shfl_xor(se, 2);
                se += __shfl_xor(se, 4);
                se += __shfl_xor(se, 8);
                se += __shfl_xor(se, 16);
                r_reg[j] = e * pu_lds[k * PUST + 16] / se;   // fold au back in
            }
            // no extra barrier: next phase touches only registers + red_a,
            // whose last readers were pre-B2 (>=2 barriers separate).
        }
    }
}

extern "C" void kernel_launch(void* const* d_in, const int* in_sizes, int n_in,
                              void* d_out, int out_size, void* d_ws, size_t ws_size,
                              hipStream_t stream) {
    const float* a_in   = (const float*)d_in[0];
    const float* pose   = (const float*)d_in[1];
    const float* W      = (const float*)d_in[2];
    const float* beta_u = (const float*)d_in[3];
    const float* beta_a = (const float*)d_in[4];
    float* out = (float*)d_out;
    (void)d_ws; (void)ws_size; (void)in_sizes; (void)n_in; (void)out_size;

    em_routing_kernel<<<dim3(8 * L_), dim3(256), 0, stream>>>(
        a_in, pose, W, beta_u, beta_a, out);
}

// Round 10
// 863.739 us; speedup vs baseline: 1.2219x; 1.2219x over previous
//
#include <hip/hip_runtime.h>
#include <math.h>

// EM routing, fully fused: one block per (b, l) output position, 256 threads.
// A=32, B=32, PSIZE=16 (4x4), K=3, STRIDE=2, PAD=1, ITERS=3.
// Input 14x14 -> output 7x7 (l = 49). kkA = 9*32 = 288.
//
// Mapping: c = tid&31 (capsule = lane bits 0-4), g = (tid>>5)&7 (k-group,
// thread owns k = 8j+g, j=0..35). r~ = r*au lives ENTIRELY in registers
// (r_reg[36], loops fully unrolled -> static indices). Softmax over c is
// intra-wave shfl butterflies. Moments: shfl_xor(32) combines the g-pair in
// each wave, then 4-wave LDS partials (s12).
//
// __launch_bounds__ calibration on this toolchain: (512,4)->VGPR cap 64,
// (512,2)->128, (256,2)->128 -- all spilled this structure (~1 GB scratch
// traffic, R7/R8). Single-arg (256) lifts the cap (up to 512 for a 4-wave
// block); natural demand ~150-200 -> 2-3 waves/SIMD, no spill. LDS 45568 B
// allows 3 blocks/CU if VGPR <= ~170.
//
// Barriers: 3/iter. WAR audit: red_a W(<B1)/R(B1..B2), next W after B2,B3.
// s12 W(B1..B2)/R(B2..B3), next W after B3,B1'. red_b W(B2..B3)/R(>B3),
// next W after B1',B2'. mu_t/is2_t W(B2..B3)/R(>B3 in P4), next W B2'..B3'.

#define KKA_    288
#define L_      49
#define OH_     7
#define EPSF    1e-12f
#define PUST    20              // pu row stride (80 B, 16B-aligned for b128)
#define S12ST   34              // s12 row stride (2-way bank alias = free)
#define LOG_LN2PI 0.60861006f   // log(log(2*pi))

__global__ __launch_bounds__(256) void em_routing_kernel(
    const float* __restrict__ a_in,   // (8, 32, 14, 14)
    const float* __restrict__ pose,   // (8, 512, 14, 14)
    const float* __restrict__ W,      // (288, 32, 4, 4)
    const float* __restrict__ beta_u, // (32)
    const float* __restrict__ beta_a, // (32)
    float* __restrict__ out)          // a_o (8,32,7,7) then pose_out (8,512,7,7)
{
    __shared__ float pu_lds[KKA_ * PUST];    // 23040 B, au[k] at pad slot 16
    __shared__ float s12[4 * 32 * S12ST];    // 17408 B per-wave S1/S2 partials
    __shared__ float red_a[4 * 32];          //   512 B rsum partials
    __shared__ float red_b[4 * 32];          //   512 B Ls partials
    __shared__ float mu_t[16 * 32];          //  2048 B mu[p][c]
    __shared__ float is2_t[16 * 32];         //  2048 B 0.5/sigma^2 [p][c]

    const int tid = threadIdx.x;
    const int bl = blockIdx.x;
    const int b  = bl / L_;
    const int l  = bl % L_;
    const int oy = l / OH_, ox = l % OH_;

    // ---- stage pu (pose unfold patch), stride-20 rows ----
    for (int q = tid; q < KKA_ * 16; q += 256) {
        const int k = q >> 4, p = q & 15;
        const int a = k & 31, kki = k >> 5;
        const int ki = kki / 3, kj = kki % 3;
        const int iy = oy * 2 + ki - 1, ix = ox * 2 + kj - 1;
        float v = 0.f;
        if ((unsigned)iy < 14u && (unsigned)ix < 14u)
            v = pose[(b * 512 + a * 16 + p) * 196 + iy * 14 + ix];
        pu_lds[k * PUST + p] = v;
    }
    // ---- stage au into pu pad slot 16 (STRIDED: 288 > 256 threads) ----
    for (int k = tid; k < KKA_; k += 256) {
        const int a = k & 31, kki = k >> 5;
        const int ki = kki / 3, kj = kki % 3;
        const int iy = oy * 2 + ki - 1, ix = ox * 2 + kj - 1;
        float v = 0.f;
        if ((unsigned)iy < 14u && (unsigned)ix < 14u)
            v = a_in[(b * 32 + a) * 196 + iy * 14 + ix];
        pu_lds[k * PUST + 16] = v;
    }
    __syncthreads();

    const int c    = tid & 31;       // capsule (lane bits 0-4)
    const int g    = (tid >> 5) & 7; // k-group 0..7 (bit0 = lane bit 5)
    const int lane = tid & 63;
    const int w    = tid >> 6;       // wave 0..3; wave w holds g in {2w,2w+1}

    const float bu_c = beta_u[c];
    const float ba_c = beta_a[c];

    // ---- r~ = r*au in registers; init r=1 -> r~ = au ----
    float r_reg[36];
    #pragma unroll
    for (int j = 0; j < 36; ++j)
        r_reg[j] = pu_lds[((j << 3) + g) * PUST + 16];

    for (int it = 0; it < 3; ++it) {
        const float lam = (it == 0) ? 0.0005f : ((it == 1) ? 0.000975f : 0.00142625f);

        // ---- step 1: rsum[c] = sum_k r~ ----
        float pa = 0.f, pb = 0.f;
        #pragma unroll
        for (int j = 0; j < 36; j += 2) { pa += r_reg[j]; pb += r_reg[j + 1]; }
        float part = pa + pb;
        part += __shfl_xor(part, 32);           // combine g-pair within wave
        if (lane < 32) red_a[w * 32 + c] = part;
        __syncthreads();                        // B1
        float rsum = 0.f;
        #pragma unroll
        for (int ww = 0; ww < 4; ++ww) rsum += red_a[ww * 32 + c];
        const float invr = 1.0f / (rsum + EPSF);

        // ---- P23: moments over this thread's 36 k's, all 16 p's ----
        float S1[16], S2[16];
        #pragma unroll
        for (int t = 0; t < 16; ++t) { S1[t] = 0.f; S2[t] = 0.f; }
        const float* pW = W + g * 512 + c * 16;
        #pragma unroll
        for (int j = 0; j < 36; ++j) {
            const int k = (j << 3) + g;
            const float cf = r_reg[j] * invr;
            const float4 w0 = *(const float4*)(pW);
            const float4 w1 = *(const float4*)(pW + 4);
            const float4 w2 = *(const float4*)(pW + 8);
            const float4 w3 = *(const float4*)(pW + 12);
            pW += 4096;
            const float* pk = &pu_lds[k * PUST];
            #pragma unroll
            for (int i = 0; i < 4; ++i) {
                const float4 pu4 = *(const float4*)(pk + (i << 2));
                float v, cv;
                v = pu4.x * w0.x + pu4.y * w1.x + pu4.z * w2.x + pu4.w * w3.x;
                cv = cf * v; S1[i * 4 + 0] += cv; S2[i * 4 + 0] += cv * v;
                v = pu4.x * w0.y + pu4.y * w1.y + pu4.z * w2.y + pu4.w * w3.y;
                cv = cf * v; S1[i * 4 + 1] += cv; S2[i * 4 + 1] += cv * v;
                v = pu4.x * w0.z + pu4.y * w1.z + pu4.z * w2.z + pu4.w * w3.z;
                cv = cf * v; S1[i * 4 + 2] += cv; S2[i * 4 + 2] += cv * v;
                v = pu4.x * w0.w + pu4.y * w1.w + pu4.z * w2.w + pu4.w * w3.w;
                cv = cf * v; S1[i * 4 + 3] += cv; S2[i * 4 + 3] += cv * v;
            }
        }
        // combine g-pair within wave, publish per-wave partials
        #pragma unroll
        for (int t = 0; t < 16; ++t) {
            S1[t] += __shfl_xor(S1[t], 32);
            S2[t] += __shfl_xor(S2[t], 32);
        }
        if (lane < 32) {
            float* dst = &s12[(w * 32 + c) * S12ST];
            #pragma unroll
            for (int t = 0; t < 16; t += 2) {
                *(float2*)(dst + t)      = make_float2(S1[t], S1[t + 1]);
                *(float2*)(dst + 16 + t) = make_float2(S2[t], S2[t + 1]);
            }
        }
        __syncthreads();                        // B2

        // ---- stats: thread (c,g) handles p = g and p = g+8 ----
        const int pA = g, pB = g + 8;
        float mA = 0.f, eA = 0.f, mB = 0.f, eB = 0.f;
        #pragma unroll
        for (int ww = 0; ww < 4; ++ww) {
            const float* src = &s12[(ww * 32 + c) * S12ST];
            mA += src[pA];      eA += src[16 + pA];
            mB += src[pB];      eB += src[16 + pB];
        }
        const float ssA = fmaxf(eA - mA * mA, 0.f) + EPSF;
        const float ssB = fmaxf(eB - mB * mB, 0.f) + EPSF;
        float lps = __logf(ssA) + __logf(ssB);
        lps += __shfl_xor(lps, 32);             // wave w: p in {2w,2w+1,2w+8,2w+9}
        if (lane < 32) red_b[w * 32 + c] = lps;
        if (it == 2) {
            out[12544 + (b * 512 + (c << 4) + pA) * 49 + l] = mA;
            out[12544 + (b * 512 + (c << 4) + pB) * 49 + l] = mB;
        } else {
            mu_t[pA * 32 + c]  = mA;  is2_t[pA * 32 + c] = 0.5f / ssA;
            mu_t[pB * 32 + c]  = mB;  is2_t[pB * 32 + c] = 0.5f / ssB;
        }
        __syncthreads();                        // B3
        float Ls = 0.f;
        #pragma unroll
        for (int ww = 0; ww < 4; ++ww) Ls += red_b[ww * 32 + c];
        const float cost = rsum * (16.f * bu_c + 0.5f * Ls);
        const float aout = 1.f / (1.f + __expf(-(lam * (ba_c - cost))));

        if (it == 2) {
            if (g == 0) out[(b * 32 + c) * 49 + l] = aout;
        } else {
            const float m1c = -0.5f * (Ls + 16.f * LOG_LN2PI) + __logf(aout);
            // ---- P4 + in-register softmax over c (intra-wave) ----
            float mu_r[16], is2_r[16];
            #pragma unroll
            for (int pp = 0; pp < 16; ++pp) {
                mu_r[pp]  = mu_t[pp * 32 + c];
                is2_r[pp] = is2_t[pp * 32 + c];
            }
            const float* pW4 = W + g * 512 + c * 16;
            #pragma unroll
            for (int j = 0; j < 36; ++j) {
                const int k = (j << 3) + g;
                const float4 wr0 = *(const float4*)(pW4);
                const float4 wr1 = *(const float4*)(pW4 + 4);
                const float4 wr2 = *(const float4*)(pW4 + 8);
                const float4 wr3 = *(const float4*)(pW4 + 12);
                pW4 += 4096;
                float q = 0.f;
                #pragma unroll
                for (int i = 0; i < 4; ++i) {
                    const float4 pui = *(const float4*)&pu_lds[k * PUST + (i << 2)];
                    float vv, d;
                    vv = pui.x * wr0.x + pui.y * wr1.x + pui.z * wr2.x + pui.w * wr3.x;
                    d = vv - mu_r[i * 4 + 0]; q += d * d * is2_r[i * 4 + 0];
                    vv = pui.x * wr0.y + pui.y * wr1.y + pui.z * wr2.y + pui.w * wr3.y;
                    d = vv - mu_r[i * 4 + 1]; q += d * d * is2_r[i * 4 + 1];
                    vv = pui.x * wr0.z + pui.y * wr1.z + pui.z * wr2.z + pui.w * wr3.z;
                    d = vv - mu_r[i * 4 + 2]; q += d * d * is2_r[i * 4 + 2];
                    vv = pui.x * wr0.w + pui.y * wr1.w + pui.z * wr2.w + pui.w * wr3.w;
                    d = vv - mu_r[i * 4 + 3]; q += d * d * is2_r[i * 4 + 3];
                }
                const float la = m1c - q;
                // softmax over the 32 c-lanes (each 32-lane half holds all c)
                float mx = la;
                mx = fmaxf(mx, __shfl_xor(mx, 1));
                mx = fmaxf(mx, __shfl_xor(mx, 2));
                mx = fmaxf(mx, __shfl_xor(mx, 4));
                mx = fmaxf(mx, __shfl_xor(mx, 8));
                mx = fmaxf(mx, __shfl_xor(mx, 16));
                const float e = __expf(la - mx);
                float se = e;
                se += __shfl_xor(se, 1);
                se += __shfl_xor(se, 2);
                se += __shfl_xor(se, 4);
                se += __shfl_xor(se, 8);
                se += __shfl_xor(se, 16);
                r_reg[j] = e * pu_lds[k * PUST + 16] / se;   // fold au back in
            }
            // no extra barrier: next phase touches only registers + red_a,
            // whose last readers were pre-B2 (>=2 barriers separate).
        }
    }
}

extern "C" void kernel_launch(void* const* d_in, const int* in_sizes, int n_in,
                              void* d_out, int out_size, void* d_ws, size_t ws_size,
                              hipStream_t stream) {
    const float* a_in   = (const float*)d_in[0];
    const float* pose   = (const float*)d_in[1];
    const float* W      = (const float*)d_in[2];
    const float* beta_u = (const float*)d_in[3];
    const float* beta_a = (const float*)d_in[4];
    float* out = (float*)d_out;
    (void)d_ws; (void)ws_size; (void)in_sizes; (void)n_in; (void)out_size;

    em_routing_kernel<<<dim3(8 * L_), dim3(256), 0, stream>>>(
        a_in, pose, W, beta_u, beta_a, out);
}

// Round 16
// 209.475 us; speedup vs baseline: 5.0385x; 4.1234x over previous
//
#include <hip/hip_runtime.h>
#include <math.h>

// EM routing, fully fused: one block per (b, l) output position, 512 threads.
// A=32, B=32, PSIZE=16 (4x4), K=3, STRIDE=2, PAD=1, ITERS=3.
// Input 14x14 -> output 7x7 (l = 49). kkA = 9*32 = 288.
//
// r lives in LDS (register-resident r spilled at every cap: R7/R8/R10).
// Phase A (c = tid>>4, sub = tid&15): 16 lanes/capsule, 18 k's each
//   (k = 16j+sub), all-16-p moments, intra-wave reduce-scatter -> lane sub
//   owns p=sub stats (static indices only). rsum/Ls via 4-step butterflies.
// Phase B (cB = tid&31, kg = tid>>5): P4 + FUSED shfl-softmax over the 32
//   c-lanes; writes r~ = r*au back to r_t. 2 barriers/iter.
//
// __launch_bounds__ calibration: 2nd arg acts as blocks/CU here.
// (512,2) -> VGPR cap 128. R6's identical inner loops measured 112 under
// this cap -> no spill expected. LDS 64768 B -> 2 blocks/CU = 4 waves/SIMD.
//
// LDS: pu[288*20] (au at col 16) 23040 | r_t[32*293] (m1 at col 292) 37504
//      | mu_t/is2_t[16*33] 2x2112. Total 64768 <= 65536.

#define KKA_    288
#define L_      49
#define OH_     7
#define EPSF    1e-12f
#define PUST    20              // pu row stride (80 B)
#define RST     293             // r_t row stride; 293%32=5, gcd(5,32)=1
#define LOG_LN2PI 0.60861006f   // log(log(2*pi))

__global__ __launch_bounds__(512, 2) void em_routing_kernel(
    const float* __restrict__ a_in,   // (8, 32, 14, 14)
    const float* __restrict__ pose,   // (8, 512, 14, 14)
    const float* __restrict__ W,      // (288, 32, 4, 4)
    const float* __restrict__ beta_u, // (32)
    const float* __restrict__ beta_a, // (32)
    float* __restrict__ out)          // a_o (8,32,7,7) then pose_out (8,512,7,7)
{
    __shared__ float pu_lds[KKA_ * PUST];    // 23040 B
    __shared__ float r_t[32 * RST];          // 37504 B
    __shared__ float mu_t[16 * 33];          //  2112 B
    __shared__ float is2_t[16 * 33];         //  2112 B

    const int tid = threadIdx.x;
    const int bl = blockIdx.x;
    const int b  = bl / L_;
    const int l  = bl % L_;
    const int oy = l / OH_, ox = l % OH_;

    // ---- stage pu (pose unfold patch), stride-20 rows ----
    for (int q = tid; q < KKA_ * 16; q += 512) {
        const int k = q >> 4, p = q & 15;
        const int a = k & 31, kki = k >> 5;
        const int ki = kki / 3, kj = kki % 3;
        const int iy = oy * 2 + ki - 1, ix = ox * 2 + kj - 1;
        float v = 0.f;
        if ((unsigned)iy < 14u && (unsigned)ix < 14u)
            v = pose[(b * 512 + a * 16 + p) * 196 + iy * 14 + ix];
        pu_lds[k * PUST + p] = v;
    }
    // ---- stage au into pu col 16 (strided loop: guard-proof) ----
    for (int k = tid; k < KKA_; k += 512) {
        const int a = k & 31, kki = k >> 5;
        const int ki = kki / 3, kj = kki % 3;
        const int iy = oy * 2 + ki - 1, ix = ox * 2 + kj - 1;
        float v = 0.f;
        if ((unsigned)iy < 14u && (unsigned)ix < 14u)
            v = a_in[(b * 32 + a) * 196 + iy * 14 + ix];
        pu_lds[k * PUST + 16] = v;
    }
    __syncthreads();
    // ---- init r_t = r*au = au (r=1) ----
    if (tid < RST) {
        const float v = (tid < KKA_) ? pu_lds[tid * PUST + 16] : 0.f;
        #pragma unroll
        for (int cc = 0; cc < 32; ++cc) r_t[cc * RST + tid] = v;
    }
    __syncthreads();

    const int sub = tid & 15;       // phase A lane-in-capsule (lane bits 0-3)
    const int cA  = tid >> 4;       // phase A capsule 0..31
    const int cB  = tid & 31;       // phase B capsule (lane bits 0-4)
    const int kg  = tid >> 5;       // phase B k-group 0..15

    const float bu_c = beta_u[cA];
    const float ba_c = beta_a[cA];
    const int rrow = cA * RST;

    for (int it = 0; it < 3; ++it) {
        const float lam = (it == 0) ? 0.0005f : ((it == 1) ? 0.000975f : 0.00142625f);

        // ---- step 1: rsum[cA] = sum_k r~ (16 lanes x 18 k's) ----
        float part = 0.f;
        #pragma unroll
        for (int j = 0; j < 18; ++j) part += r_t[rrow + 16 * j + sub];
        part += __shfl_xor(part, 1);
        part += __shfl_xor(part, 2);
        part += __shfl_xor(part, 4);
        part += __shfl_xor(part, 8);
        const float rsum = part;
        const float invr = 1.0f / (rsum + EPSF);

        // ---- P23: moments over 18 k's, all 16 p's ----
        float S1[16], S2[16];
        #pragma unroll
        for (int t = 0; t < 16; ++t) { S1[t] = 0.f; S2[t] = 0.f; }
        const float* pW = W + sub * 512 + cA * 16;
        #pragma unroll 2
        for (int j = 0; j < 18; ++j) {
            const int k = 16 * j + sub;
            const float cf = r_t[rrow + k] * invr;
            const float4 w0 = *(const float4*)(pW);
            const float4 w1 = *(const float4*)(pW + 4);
            const float4 w2 = *(const float4*)(pW + 8);
            const float4 w3 = *(const float4*)(pW + 12);
            pW += 8192;
            const float* pk = &pu_lds[k * PUST];
            #pragma unroll
            for (int i = 0; i < 4; ++i) {
                const float4 pu4 = *(const float4*)(pk + (i << 2));
                float v, cv;
                v = pu4.x * w0.x + pu4.y * w1.x + pu4.z * w2.x + pu4.w * w3.x;
                cv = cf * v; S1[i * 4 + 0] += cv; S2[i * 4 + 0] += cv * v;
                v = pu4.x * w0.y + pu4.y * w1.y + pu4.z * w2.y + pu4.w * w3.y;
                cv = cf * v; S1[i * 4 + 1] += cv; S2[i * 4 + 1] += cv * v;
                v = pu4.x * w0.z + pu4.y * w1.z + pu4.z * w2.z + pu4.w * w3.z;
                cv = cf * v; S1[i * 4 + 2] += cv; S2[i * 4 + 2] += cv * v;
                v = pu4.x * w0.w + pu4.y * w1.w + pu4.z * w2.w + pu4.w * w3.w;
                cv = cf * v; S1[i * 4 + 3] += cv; S2[i * 4 + 3] += cv * v;
            }
        }
        // ---- reduce-scatter over the 16 sub-lanes: lane sub ends owning
        //      the full sums for p = sub. Static indices + predicated selects.
        float a1[8], a2[8];
        {
            const bool hi = (sub & 8) != 0;
            #pragma unroll
            for (int i = 0; i < 8; ++i) {
                const float s1 = hi ? S1[i] : S1[8 + i];
                const float k1 = hi ? S1[8 + i] : S1[i];
                a1[i] = k1 + __shfl_xor(s1, 8);
                const float s2 = hi ? S2[i] : S2[8 + i];
                const float k2 = hi ? S2[8 + i] : S2[i];
                a2[i] = k2 + __shfl_xor(s2, 8);
            }
        }
        float b1[4], b2[4];
        {
            const bool hi = (sub & 4) != 0;
            #pragma unroll
            for (int i = 0; i < 4; ++i) {
                const float s1 = hi ? a1[i] : a1[4 + i];
                const float k1 = hi ? a1[4 + i] : a1[i];
                b1[i] = k1 + __shfl_xor(s1, 4);
                const float s2 = hi ? a2[i] : a2[4 + i];
                const float k2 = hi ? a2[4 + i] : a2[i];
                b2[i] = k2 + __shfl_xor(s2, 4);
            }
        }
        float c1[2], c2[2];
        {
            const bool hi = (sub & 2) != 0;
            #pragma unroll
            for (int i = 0; i < 2; ++i) {
                const float s1 = hi ? b1[i] : b1[2 + i];
                const float k1 = hi ? b1[2 + i] : b1[i];
                c1[i] = k1 + __shfl_xor(s1, 2);
                const float s2 = hi ? b2[i] : b2[2 + i];
                const float k2 = hi ? b2[2 + i] : b2[i];
                c2[i] = k2 + __shfl_xor(s2, 2);
            }
        }
        float m, e2;
        {
            const bool hi = (sub & 1) != 0;
            const float s1 = hi ? c1[0] : c1[1];
            const float k1 = hi ? c1[1] : c1[0];
            m = k1 + __shfl_xor(s1, 1);
            const float s2 = hi ? c2[0] : c2[1];
            const float k2 = hi ? c2[1] : c2[0];
            e2 = k2 + __shfl_xor(s2, 1);
        }

        // ---- stats for p = sub ----
        const float ss = fmaxf(e2 - m * m, 0.f) + EPSF;
        float Ls = __logf(ss);
        Ls += __shfl_xor(Ls, 1);
        Ls += __shfl_xor(Ls, 2);
        Ls += __shfl_xor(Ls, 4);
        Ls += __shfl_xor(Ls, 8);                 // sum_p log(ss)
        if (it == 2) {
            out[12544 + (b * 512 + (cA << 4) + sub) * 49 + l] = m;
        } else {
            mu_t[sub * 33 + cA]  = m;
            is2_t[sub * 33 + cA] = 0.5f / ss;
        }
        const float cost = rsum * (16.f * bu_c + 0.5f * Ls);
        const float aout = 1.f / (1.f + __expf(-(lam * (ba_c - cost))));

        if (it == 2) {
            if (sub == 0) out[(b * 32 + cA) * 49 + l] = aout;
        } else {
            if (sub == 0)
                r_t[rrow + 292] = -0.5f * (Ls + 16.f * LOG_LN2PI) + __logf(aout);
            __syncthreads();                     // B1

            // ---- phase B: P4 + fused softmax over c (intra-wave) ----
            float mu_r[16], is2_r[16];
            #pragma unroll
            for (int pp = 0; pp < 16; ++pp) {
                mu_r[pp]  = mu_t[pp * 33 + cB];
                is2_r[pp] = is2_t[pp * 33 + cB];
            }
            const float m1c = r_t[cB * RST + 292];
            const float* pW4 = W + kg * 512 + cB * 16;
            #pragma unroll 2
            for (int j = 0; j < 18; ++j) {
                const int k = 16 * j + kg;
                const float4 wr0 = *(const float4*)(pW4);
                const float4 wr1 = *(const float4*)(pW4 + 4);
                const float4 wr2 = *(const float4*)(pW4 + 8);
                const float4 wr3 = *(const float4*)(pW4 + 12);
                pW4 += 8192;
                float q = 0.f;
                #pragma unroll
                for (int i = 0; i < 4; ++i) {
                    const float4 pui = *(const float4*)&pu_lds[k * PUST + (i << 2)];
                    float vv, d;
                    vv = pui.x * wr0.x + pui.y * wr1.x + pui.z * wr2.x + pui.w * wr3.x;
                    d = vv - mu_r[i * 4 + 0]; q += d * d * is2_r[i * 4 + 0];
                    vv = pui.x * wr0.y + pui.y * wr1.y + pui.z * wr2.y + pui.w * wr3.y;
                    d = vv - mu_r[i * 4 + 1]; q += d * d * is2_r[i * 4 + 1];
                    vv = pui.x * wr0.z + pui.y * wr1.z + pui.z * wr2.z + pui.w * wr3.z;
                    d = vv - mu_r[i * 4 + 2]; q += d * d * is2_r[i * 4 + 2];
                    vv = pui.x * wr0.w + pui.y * wr1.w + pui.z * wr2.w + pui.w * wr3.w;
                    d = vv - mu_r[i * 4 + 3]; q += d * d * is2_r[i * 4 + 3];
                }
                const float la = m1c - q;
                // softmax over the 32 c-lanes
                float mx = la;
                mx = fmaxf(mx, __shfl_xor(mx, 1));
                mx = fmaxf(mx, __shfl_xor(mx, 2));
                mx = fmaxf(mx, __shfl_xor(mx, 4));
                mx = fmaxf(mx, __shfl_xor(mx, 8));
                mx = fmaxf(mx, __shfl_xor(mx, 16));
                const float e = __expf(la - mx);
                float se = e;
                se += __shfl_xor(se, 1);
                se += __shfl_xor(se, 2);
                se += __shfl_xor(se, 4);
                se += __shfl_xor(se, 8);
                se += __shfl_xor(se, 16);
                r_t[cB * RST + k] = e * pu_lds[k * PUST + 16] / se;
            }
            __syncthreads();                     // B2
        }
    }
}

extern "C" void kernel_launch(void* const* d_in, const int* in_sizes, int n_in,
                              void* d_out, int out_size, void* d_ws, size_t ws_size,
                              hipStream_t stream) {
    const float* a_in   = (const float*)d_in[0];
    const float* pose   = (const float*)d_in[1];
    const float* W      = (const float*)d_in[2];
    const float* beta_u = (const float*)d_in[3];
    const float* beta_a = (const float*)d_in[4];
    float* out = (float*)d_out;
    (void)d_ws; (void)ws_size; (void)in_sizes; (void)n_in; (void)out_size;

    em_routing_kernel<<<dim3(8 * L_), dim3(512), 0, stream>>>(
        a_in, pose, W, beta_u, beta_a, out);
}

// Round 17
// 208.802 us; speedup vs baseline: 5.0547x; 1.0032x over previous
//
#include <hip/hip_runtime.h>
#include <math.h>

// EM routing, fully fused: one block per (b, l) output position, 512 threads.
// A=32, B=32, PSIZE=16 (4x4), K=3, STRIDE=2, PAD=1, ITERS=3.
// Input 14x14 -> output 7x7 (l = 49). kkA = 9*32 = 288.
//
// r lives in LDS (register-resident r spilled at every cap: R7/R8/R10).
// Phase A (c = tid>>4, sub = tid&15): 16 lanes/capsule, 18 k's each
//   (k = 16j+sub), all-16-p moments, intra-wave reduce-scatter -> lane sub
//   owns p=sub stats (static indices only). rsum/Ls via 4-step butterflies.
// Phase B (cB = tid&31, kg = tid>>5): P4 + FUSED shfl-softmax over the 32
//   c-lanes; writes r~ = r*au back to r_t. 2 barriers/iter.
//
// R16 measured: 160us, VGPR 56, VALUBusy 31.7%, Occ 28.3%, no spill.
// Stall is per-wave ILP (dependent W-load/LDS-read clusters, unroll-2 = only
// 2 iters in flight) -> deepen pipeline: unroll 6 on both j-loops, spending
// the 72 spare VGPRs on in-flight loads. (512,2) -> VGPR cap 128 unchanged.
//
// LDS: pu[288*20] (au at col 16) 23040 | r_t[32*293] (m1 at col 292) 37504
//      | mu_t/is2_t[16*33] 2x2112. Total 64768 <= 65536.

#define KKA_    288
#define L_      49
#define OH_     7
#define EPSF    1e-12f
#define PUST    20              // pu row stride (80 B)
#define RST     293             // r_t row stride; 293%32=5, gcd(5,32)=1
#define LOG_LN2PI 0.60861006f   // log(log(2*pi))

__global__ __launch_bounds__(512, 2) void em_routing_kernel(
    const float* __restrict__ a_in,   // (8, 32, 14, 14)
    const float* __restrict__ pose,   // (8, 512, 14, 14)
    const float* __restrict__ W,      // (288, 32, 4, 4)
    const float* __restrict__ beta_u, // (32)
    const float* __restrict__ beta_a, // (32)
    float* __restrict__ out)          // a_o (8,32,7,7) then pose_out (8,512,7,7)
{
    __shared__ float pu_lds[KKA_ * PUST];    // 23040 B
    __shared__ float r_t[32 * RST];          // 37504 B
    __shared__ float mu_t[16 * 33];          //  2112 B
    __shared__ float is2_t[16 * 33];         //  2112 B

    const int tid = threadIdx.x;
    const int bl = blockIdx.x;
    const int b  = bl / L_;
    const int l  = bl % L_;
    const int oy = l / OH_, ox = l % OH_;

    // ---- stage pu (pose unfold patch), stride-20 rows ----
    for (int q = tid; q < KKA_ * 16; q += 512) {
        const int k = q >> 4, p = q & 15;
        const int a = k & 31, kki = k >> 5;
        const int ki = kki / 3, kj = kki % 3;
        const int iy = oy * 2 + ki - 1, ix = ox * 2 + kj - 1;
        float v = 0.f;
        if ((unsigned)iy < 14u && (unsigned)ix < 14u)
            v = pose[(b * 512 + a * 16 + p) * 196 + iy * 14 + ix];
        pu_lds[k * PUST + p] = v;
    }
    // ---- stage au into pu col 16 (strided loop: guard-proof) ----
    for (int k = tid; k < KKA_; k += 512) {
        const int a = k & 31, kki = k >> 5;
        const int ki = kki / 3, kj = kki % 3;
        const int iy = oy * 2 + ki - 1, ix = ox * 2 + kj - 1;
        float v = 0.f;
        if ((unsigned)iy < 14u && (unsigned)ix < 14u)
            v = a_in[(b * 32 + a) * 196 + iy * 14 + ix];
        pu_lds[k * PUST + 16] = v;
    }
    __syncthreads();
    // ---- init r_t = r*au = au (r=1) ----
    if (tid < RST) {
        const float v = (tid < KKA_) ? pu_lds[tid * PUST + 16] : 0.f;
        #pragma unroll
        for (int cc = 0; cc < 32; ++cc) r_t[cc * RST + tid] = v;
    }
    __syncthreads();

    const int sub = tid & 15;       // phase A lane-in-capsule (lane bits 0-3)
    const int cA  = tid >> 4;       // phase A capsule 0..31
    const int cB  = tid & 31;       // phase B capsule (lane bits 0-4)
    const int kg  = tid >> 5;       // phase B k-group 0..15

    const float bu_c = beta_u[cA];
    const float ba_c = beta_a[cA];
    const int rrow = cA * RST;

    for (int it = 0; it < 3; ++it) {
        const float lam = (it == 0) ? 0.0005f : ((it == 1) ? 0.000975f : 0.00142625f);

        // ---- step 1: rsum[cA] = sum_k r~ (16 lanes x 18 k's) ----
        float part = 0.f;
        #pragma unroll
        for (int j = 0; j < 18; ++j) part += r_t[rrow + 16 * j + sub];
        part += __shfl_xor(part, 1);
        part += __shfl_xor(part, 2);
        part += __shfl_xor(part, 4);
        part += __shfl_xor(part, 8);
        const float rsum = part;
        const float invr = 1.0f / (rsum + EPSF);

        // ---- P23: moments over 18 k's, all 16 p's (6-deep pipeline) ----
        float S1[16], S2[16];
        #pragma unroll
        for (int t = 0; t < 16; ++t) { S1[t] = 0.f; S2[t] = 0.f; }
        const float* pW = W + sub * 512 + cA * 16;
        #pragma unroll 6
        for (int j = 0; j < 18; ++j) {
            const int k = 16 * j + sub;
            const float cf = r_t[rrow + k] * invr;
            const float4 w0 = *(const float4*)(pW);
            const float4 w1 = *(const float4*)(pW + 4);
            const float4 w2 = *(const float4*)(pW + 8);
            const float4 w3 = *(const float4*)(pW + 12);
            pW += 8192;
            const float* pk = &pu_lds[k * PUST];
            #pragma unroll
            for (int i = 0; i < 4; ++i) {
                const float4 pu4 = *(const float4*)(pk + (i << 2));
                float v, cv;
                v = pu4.x * w0.x + pu4.y * w1.x + pu4.z * w2.x + pu4.w * w3.x;
                cv = cf * v; S1[i * 4 + 0] += cv; S2[i * 4 + 0] += cv * v;
                v = pu4.x * w0.y + pu4.y * w1.y + pu4.z * w2.y + pu4.w * w3.y;
                cv = cf * v; S1[i * 4 + 1] += cv; S2[i * 4 + 1] += cv * v;
                v = pu4.x * w0.z + pu4.y * w1.z + pu4.z * w2.z + pu4.w * w3.z;
                cv = cf * v; S1[i * 4 + 2] += cv; S2[i * 4 + 2] += cv * v;
                v = pu4.x * w0.w + pu4.y * w1.w + pu4.z * w2.w + pu4.w * w3.w;
                cv = cf * v; S1[i * 4 + 3] += cv; S2[i * 4 + 3] += cv * v;
            }
        }
        // ---- reduce-scatter over the 16 sub-lanes: lane sub ends owning
        //      the full sums for p = sub. Static indices + predicated selects.
        float a1[8], a2[8];
        {
            const bool hi = (sub & 8) != 0;
            #pragma unroll
            for (int i = 0; i < 8; ++i) {
                const float s1 = hi ? S1[i] : S1[8 + i];
                const float k1 = hi ? S1[8 + i] : S1[i];
                a1[i] = k1 + __shfl_xor(s1, 8);
                const float s2 = hi ? S2[i] : S2[8 + i];
                const float k2 = hi ? S2[8 + i] : S2[i];
                a2[i] = k2 + __shfl_xor(s2, 8);
            }
        }
        float b1[4], b2[4];
        {
            const bool hi = (sub & 4) != 0;
            #pragma unroll
            for (int i = 0; i < 4; ++i) {
                const float s1 = hi ? a1[i] : a1[4 + i];
                const float k1 = hi ? a1[4 + i] : a1[i];
                b1[i] = k1 + __shfl_xor(s1, 4);
                const float s2 = hi ? a2[i] : a2[4 + i];
                const float k2 = hi ? a2[4 + i] : a2[i];
                b2[i] = k2 + __shfl_xor(s2, 4);
            }
        }
        float c1[2], c2[2];
        {
            const bool hi = (sub & 2) != 0;
            #pragma unroll
            for (int i = 0; i < 2; ++i) {
                const float s1 = hi ? b1[i] : b1[2 + i];
                const float k1 = hi ? b1[2 + i] : b1[i];
                c1[i] = k1 + __shfl_xor(s1, 2);
                const float s2 = hi ? b2[i] : b2[2 + i];
                const float k2 = hi ? b2[2 + i] : b2[i];
                c2[i] = k2 + __shfl_xor(s2, 2);
            }
        }
        float m, e2;
        {
            const bool hi = (sub & 1) != 0;
            const float s1 = hi ? c1[0] : c1[1];
            const float k1 = hi ? c1[1] : c1[0];
            m = k1 + __shfl_xor(s1, 1);
            const float s2 = hi ? c2[0] : c2[1];
            const float k2 = hi ? c2[1] : c2[0];
            e2 = k2 + __shfl_xor(s2, 1);
        }

        // ---- stats for p = sub ----
        const float ss = fmaxf(e2 - m * m, 0.f) + EPSF;
        float Ls = __logf(ss);
        Ls += __shfl_xor(Ls, 1);
        Ls += __shfl_xor(Ls, 2);
        Ls += __shfl_xor(Ls, 4);
        Ls += __shfl_xor(Ls, 8);                 // sum_p log(ss)
        if (it == 2) {
            out[12544 + (b * 512 + (cA << 4) + sub) * 49 + l] = m;
        } else {
            mu_t[sub * 33 + cA]  = m;
            is2_t[sub * 33 + cA] = 0.5f / ss;
        }
        const float cost = rsum * (16.f * bu_c + 0.5f * Ls);
        const float aout = 1.f / (1.f + __expf(-(lam * (ba_c - cost))));

        if (it == 2) {
            if (sub == 0) out[(b * 32 + cA) * 49 + l] = aout;
        } else {
            if (sub == 0)
                r_t[rrow + 292] = -0.5f * (Ls + 16.f * LOG_LN2PI) + __logf(aout);
            __syncthreads();                     // B1

            // ---- phase B: P4 + fused softmax over c (6-deep pipeline) ----
            float mu_r[16], is2_r[16];
            #pragma unroll
            for (int pp = 0; pp < 16; ++pp) {
                mu_r[pp]  = mu_t[pp * 33 + cB];
                is2_r[pp] = is2_t[pp * 33 + cB];
            }
            const float m1c = r_t[cB * RST + 292];
            const float* pW4 = W + kg * 512 + cB * 16;
            #pragma unroll 6
            for (int j = 0; j < 18; ++j) {
                const int k = 16 * j + kg;
                const float4 wr0 = *(const float4*)(pW4);
                const float4 wr1 = *(const float4*)(pW4 + 4);
                const float4 wr2 = *(const float4*)(pW4 + 8);
                const float4 wr3 = *(const float4*)(pW4 + 12);
                pW4 += 8192;
                float q = 0.f;
                #pragma unroll
                for (int i = 0; i < 4; ++i) {
                    const float4 pui = *(const float4*)&pu_lds[k * PUST + (i << 2)];
                    float vv, d;
                    vv = pui.x * wr0.x + pui.y * wr1.x + pui.z * wr2.x + pui.w * wr3.x;
                    d = vv - mu_r[i * 4 + 0]; q += d * d * is2_r[i * 4 + 0];
                    vv = pui.x * wr0.y + pui.y * wr1.y + pui.z * wr2.y + pui.w * wr3.y;
                    d = vv - mu_r[i * 4 + 1]; q += d * d * is2_r[i * 4 + 1];
                    vv = pui.x * wr0.z + pui.y * wr1.z + pui.z * wr2.z + pui.w * wr3.z;
                    d = vv - mu_r[i * 4 + 2]; q += d * d * is2_r[i * 4 + 2];
                    vv = pui.x * wr0.w + pui.y * wr1.w + pui.z * wr2.w + pui.w * wr3.w;
                    d = vv - mu_r[i * 4 + 3]; q += d * d * is2_r[i * 4 + 3];
                }
                const float la = m1c - q;
                // softmax over the 32 c-lanes
                float mx = la;
                mx = fmaxf(mx, __shfl_xor(mx, 1));
                mx = fmaxf(mx, __shfl_xor(mx, 2));
                mx = fmaxf(mx, __shfl_xor(mx, 4));
                mx = fmaxf(mx, __shfl_xor(mx, 8));
                mx = fmaxf(mx, __shfl_xor(mx, 16));
                const float e = __expf(la - mx);
                float se = e;
                se += __shfl_xor(se, 1);
                se += __shfl_xor(se, 2);
                se += __shfl_xor(se, 4);
                se += __shfl_xor(se, 8);
                se += __shfl_xor(se, 16);
                r_t[cB * RST + k] = e * pu_lds[k * PUST + 16] / se;
            }
            __syncthreads();                     // B2
        }
    }
}

extern "C" void kernel_launch(void* const* d_in, const int* in_sizes, int n_in,
                              void* d_out, int out_size, void* d_ws, size_t ws_size,
                              hipStream_t stream) {
    const float* a_in   = (const float*)d_in[0];
    const float* pose   = (const float*)d_in[1];
    const float* W      = (const float*)d_in[2];
    const float* beta_u = (const float*)d_in[3];
    const float* beta_a = (const float*)d_in[4];
    float* out = (float*)d_out;
    (void)d_ws; (void)ws_size; (void)in_sizes; (void)n_in; (void)out_size;

    em_routing_kernel<<<dim3(8 * L_), dim3(512), 0, stream>>>(
        a_in, pose, W, beta_u, beta_a, out);
}